// Round 5
// baseline (514.965 us; speedup 1.0000x reference)
//
#include <hip/hip_runtime.h>

// MultiheadCrossAttention: B=4, SQ=SK=2048, D=1024, H=16, HD=64.
// bf16 MFMA 16x16x32, fp32 accum.
// ws (big, 104MB): [W16 8][q16 16][k16 16][vt16 16][qf 16][kf 16][vf 16]; o16 aliases qf.
// ws (small, 72MB): [W16 8][q16 16][k16 16][vt16 16][o16 16], A stays fp32 in GEMM.
// GEMMs: 256x128 tile, 512 thr, BK=64 frag-major LDS, dbuf, 1 barrier/iter.
// attn: S^T = K·Q^T -> P in registers (key->slot perm baked into vt16);
//       2 q-tiles/block, K/V/mask dbuf, 1 barrier/tile, l via ones-MFMA,
//       XCD swizzle: all 8 qt-blocks of one bh land on one XCD (K/V L2-resident).

typedef __bf16 bf16_t;
typedef __attribute__((ext_vector_type(2))) __bf16 bf16x2;
typedef __attribute__((ext_vector_type(4))) __bf16 bf16x4;
typedef __attribute__((ext_vector_type(8))) __bf16 bf16x8;
typedef __attribute__((ext_vector_type(4))) float f32x4;

#define MFMA16(a, b, c) __builtin_amdgcn_mfma_f32_16x16x32_bf16(a, b, c, 0, 0, 0)

__device__ __forceinline__ void gl_lds16(const void* g, void* l) {
  __builtin_amdgcn_global_load_lds(
      (const __attribute__((address_space(1))) unsigned int*)g,
      (__attribute__((address_space(3))) unsigned int*)l, 16, 0, 0);
}

__device__ __forceinline__ bf16x2 cvt_pk_bf16(float a, float b) {
#if __has_builtin(__builtin_amdgcn_cvt_pk_bf16_f32)
  return __builtin_amdgcn_cvt_pk_bf16_f32(a, b);
#else
  bf16x2 r;
  r[0] = (bf16_t)a;
  r[1] = (bf16_t)b;
  return r;
#endif
}

// ---------------- fp32 -> bf16 conversion (weights + optionally activations) ----
// chunk = 1024 elems. chunks [0,4096): W q/k/v/o. chunks [4096,...): q,k,v inputs.
__global__ void conv_kernel(const float* __restrict__ q, const float* __restrict__ k,
                            const float* __restrict__ v, const float* __restrict__ Wq,
                            const float* __restrict__ Wk, const float* __restrict__ Wv,
                            const float* __restrict__ Wo, bf16_t* __restrict__ qf,
                            bf16_t* __restrict__ kf, bf16_t* __restrict__ vf,
                            bf16_t* __restrict__ W16) {
  const int c = blockIdx.x;
  const float* src;
  bf16_t* dst;
  if (c < 4096) {
    const int w = c >> 10;
    src = (w == 0) ? Wq : (w == 1) ? Wk : (w == 2) ? Wv : Wo;
    dst = W16 + ((size_t)w << 20);
    const size_t off = (size_t)(c & 1023) * 1024;
    src += off;
    dst += off;
  } else {
    const int a = c - 4096;
    const int which = a >> 13;
    src = (which == 0) ? q : (which == 1) ? k : v;
    dst = (which == 0) ? qf : (which == 1) ? kf : vf;
    const size_t off = (size_t)(a & 8191) * 1024;
    src += off;
    dst += off;
  }
  const int idx = threadIdx.x * 4;
  float4 x = *(const float4*)(src + idx);
  bf16x4 pk;
  pk[0] = (bf16_t)x.x; pk[1] = (bf16_t)x.y; pk[2] = (bf16_t)x.z; pk[3] = (bf16_t)x.w;
  *(bf16x4*)(dst + idx) = pk;
}

// ---------------- GEMM 256x128, 512 threads, BK=64 dbuf ----------------
struct GArgs {
  const void* A[3];
  const bf16_t* Wz[3];
  const float* bias[3];
  void* out[3];
  int mode[3];  // 0 = bf16 row-major, 1 = bf16 vt-permuted, 2 = fp32
};

template <bool A_F32>
__global__ __launch_bounds__(512, 1) void gemm256(GArgs g) {
  __shared__ __align__(16) bf16_t As[2][32 * 512];  // 32 KB each
  __shared__ __align__(16) bf16_t Bs[2][16 * 512];  // 16 KB each

  const int z = blockIdx.z;
  const bf16_t* Bw = g.Wz[z];
  const float* bias = g.bias[z];
  const int mode = g.mode[z];

  const int tid = threadIdx.x;
  const int lane = tid & 63, wave = tid >> 6;  // 8 waves
  const int fm = lane & 15, quad = lane >> 4;
  const int wr = wave >> 1, wc = wave & 1;  // wave tile 64x64 at (wr*64, wc*64)
  const int M0 = blockIdx.x * 256, N0 = blockIdx.y * 128;

  f32x4 acc[4][4];
#pragma unroll
  for (int i = 0; i < 4; ++i)
#pragma unroll
    for (int j = 0; j < 4; ++j) acc[i][j] = f32x4{0.f, 0.f, 0.f, 0.f};

  float4 areg[4][2];
  auto loadA = [&](int ks) {
    const float* A = (const float*)g.A[z];
#pragma unroll
    for (int it = 0; it < 4; ++it) {
      const int afid = wave * 4 + it;
      const int row = (afid >> 1) * 16 + fm;
      const int col = (afid & 1) * 32 + quad * 8;
      const float* s = A + (size_t)(M0 + row) * 1024 + ks * 64 + col;
      areg[it][0] = *(const float4*)s;
      areg[it][1] = *(const float4*)(s + 4);
    }
  };
  auto writeA = [&](int buf) {
#pragma unroll
    for (int it = 0; it < 4; ++it) {
      const int afid = wave * 4 + it;
      bf16x8 pk;
      bf16x2* p2 = (bf16x2*)&pk;
      p2[0] = cvt_pk_bf16(areg[it][0].x, areg[it][0].y);
      p2[1] = cvt_pk_bf16(areg[it][0].z, areg[it][0].w);
      p2[2] = cvt_pk_bf16(areg[it][1].x, areg[it][1].y);
      p2[3] = cvt_pk_bf16(areg[it][1].z, areg[it][1].w);
      *(bf16x8*)(As[buf] + afid * 512 + lane * 8) = pk;
    }
  };
  auto dmaA = [&](int ks, int buf) {
    const bf16_t* A = (const bf16_t*)g.A[z];
#pragma unroll
    for (int it = 0; it < 4; ++it) {
      const int afid = wave * 4 + it;
      const int row = (afid >> 1) * 16 + fm;
      const int col = (afid & 1) * 32 + quad * 8;
      gl_lds16(A + (size_t)(M0 + row) * 1024 + ks * 64 + col, As[buf] + afid * 512);
    }
  };
  auto dmaB = [&](int ks, int buf) {
#pragma unroll
    for (int it = 0; it < 2; ++it) {
      const int bfid = wave * 2 + it;
      const int row = (bfid >> 1) * 16 + fm;
      const int col = (bfid & 1) * 32 + quad * 8;
      gl_lds16(Bw + (size_t)(N0 + row) * 1024 + ks * 64 + col, Bs[buf] + bfid * 512);
    }
  };

  if constexpr (A_F32) {
    loadA(0);
    writeA(0);
    dmaB(0, 0);
  } else {
    dmaA(0, 0);
    dmaB(0, 0);
  }

  for (int ks = 0; ks < 16; ++ks) {
    __syncthreads();  // drains DMA for buf[ks&1]
    const int nb = (ks + 1) & 1;
    if (ks < 15) {
      if constexpr (A_F32) {
        loadA(ks + 1);  // waited in writeA AFTER compute
      } else {
        dmaA(ks + 1, nb);
      }
      dmaB(ks + 1, nb);
    }
    const bf16_t* Ab = As[ks & 1];
    const bf16_t* Bb = Bs[ks & 1];
#pragma unroll
    for (int u = 0; u < 2; ++u) {
      bf16x8 af[4], bfr[4];
#pragma unroll
      for (int i = 0; i < 4; ++i)
        af[i] = *(const bf16x8*)(Ab + ((4 * wr + i) * 2 + u) * 512 + lane * 8);
#pragma unroll
      for (int j = 0; j < 4; ++j)
        bfr[j] = *(const bf16x8*)(Bb + ((4 * wc + j) * 2 + u) * 512 + lane * 8);
#pragma unroll
      for (int i = 0; i < 4; ++i)
#pragma unroll
        for (int j = 0; j < 4; ++j) acc[i][j] = MFMA16(af[i], bfr[j], acc[i][j]);
    }
    if constexpr (A_F32) {
      if (ks < 15) writeA(nb);
    }
  }

  float bval[4];
#pragma unroll
  for (int j = 0; j < 4; ++j) bval[j] = bias[N0 + wc * 64 + j * 16 + fm];

#pragma unroll
  for (int i = 0; i < 4; ++i) {
#pragma unroll
    for (int j = 0; j < 4; ++j) {
      const int col = N0 + wc * 64 + j * 16 + fm;
#pragma unroll
      for (int r = 0; r < 4; ++r) {
        const int row = M0 + wr * 64 + i * 16 + quad * 4 + r;
        const float v = acc[i][j][r] + bval[j];
        if (mode == 2) {
          ((float*)g.out[z])[(size_t)row * 1024 + col] = v;
        } else if (mode == 0) {
          ((bf16_t*)g.out[z])[(size_t)row * 1024 + col] = (bf16_t)v;
        } else {
          // vt16 permuted: per (bh, t128) tile, frag-major (nt,c) x lane x j
          const int bb = row >> 11, sk = row & 2047;
          const int tt = sk >> 7, L128 = sk & 127;
          const int c = L128 >> 5, hf = (L128 >> 4) & 1;
          const int qd = (L128 >> 2) & 3, rr = L128 & 3;
          const int hh = col >> 6, hd = col & 63;
          const int nt = hd >> 4, fv = hd & 15;
          const size_t idx = (((size_t)(bb * 16 + hh)) << 17) + tt * 8192 +
                             (nt * 4 + c) * 512 + (qd * 16 + fv) * 8 + hf * 4 + rr;
          ((bf16_t*)g.out[z])[idx] = (bf16_t)v;
        }
      }
    }
  }
}

// ---------------- flash attention ----------------
// 512 blocks x 256 thr; block handles 2 q-tiles (256 q rows) x full SK.
// Swizzle: all 8 qt-blocks of one bh share an XCD -> K/V slab L2-resident.
__global__ __launch_bounds__(256, 2) void attn_kernel(
    const bf16_t* __restrict__ q16, const bf16_t* __restrict__ k16,
    const bf16_t* __restrict__ vt16, const int* __restrict__ mask,
    bf16_t* __restrict__ o16) {
  __shared__ __align__(16) bf16_t Kb[2][8192];
  __shared__ __align__(16) bf16_t Vb[2][8192];
  __shared__ float mb[2][128];

  const int tid = threadIdx.x;
  const int lane = tid & 63, wave = tid >> 6;
  const int fm = lane & 15, quad = lane >> 4;
  const int linear = blockIdx.x;
  const int bh = (linear & 7) * 8 + ((linear >> 3) & 7);
  const int qt = linear >> 6;
  const int b = bh >> 4, h = bh & 15;
  const float SC = 0.125f * 1.44269504f;  // HD^-0.5 * log2(e)

  // Q -> registers (B-operand of S^T), 2 q-halves of 128 rows
  bf16x8 aq[2][2][2];
#pragma unroll
  for (int gq = 0; gq < 2; ++gq)
#pragma unroll
    for (int i = 0; i < 2; ++i)
#pragma unroll
      for (int dc = 0; dc < 2; ++dc) {
        const int row = qt * 256 + gq * 128 + (2 * wave + i) * 16 + fm;
        aq[gq][i][dc] = *(const bf16x8*)(q16 + ((size_t)(b * 2048 + row)) * 1024 +
                                         h * 64 + dc * 32 + quad * 8);
      }

  auto stageKV = [&](int t, int buf) {
    const bf16_t* kb = k16 + ((size_t)(b * 2048 + t * 128)) * 1024 + h * 64;
#pragma unroll
    for (int s = 0; s < 4; ++s) {
      const int fid = wave * 4 + s;
      const int row = (fid >> 1) * 16 + fm;
      const int col = (fid & 1) * 32 + quad * 8;
      gl_lds16(kb + (size_t)row * 1024 + col, Kb[buf] + fid * 512);
    }
    const bf16_t* vb = vt16 + ((size_t)bh << 17) + t * 8192;
#pragma unroll
    for (int s = 0; s < 4; ++s) {
      const int fid = wave * 4 + s;
      gl_lds16(vb + fid * 512 + lane * 8, Vb[buf] + fid * 512);
    }
    if (tid < 32) {
      int4 m4 = *(const int4*)(mask + b * 2048 + t * 128 + tid * 4);
      float4 f{m4.x ? 0.f : -1e30f, m4.y ? 0.f : -1e30f, m4.z ? 0.f : -1e30f,
               m4.w ? 0.f : -1e30f};
      *(float4*)&mb[buf][tid * 4] = f;
    }
  };

  f32x4 oacc[2][2][4];
#pragma unroll
  for (int gq = 0; gq < 2; ++gq)
#pragma unroll
    for (int i = 0; i < 2; ++i)
#pragma unroll
      for (int n = 0; n < 4; ++n) oacc[gq][i][n] = f32x4{0.f, 0.f, 0.f, 0.f};
  f32x4 lacc[2][2];
#pragma unroll
  for (int gq = 0; gq < 2; ++gq)
#pragma unroll
    for (int i = 0; i < 2; ++i) lacc[gq][i] = f32x4{0.f, 0.f, 0.f, 0.f};
  bf16x8 ones;
#pragma unroll
  for (int e = 0; e < 8; ++e) ones[e] = (bf16_t)1.0f;

  stageKV(0, 0);
  for (int t = 0; t < 16; ++t) {
    __syncthreads();  // drains stage(t) DMA (issued one full tile ago)
    if (t < 15) stageKV(t + 1, (t + 1) & 1);
    const bf16_t* K = Kb[t & 1];
    const bf16_t* V = Vb[t & 1];
    const float* mrow = mb[t & 1];

#pragma unroll
    for (int gq = 0; gq < 2; ++gq) {
      // S^T = K Q^T
      f32x4 sacc[2][8];
#pragma unroll
      for (int i = 0; i < 2; ++i)
#pragma unroll
        for (int j = 0; j < 8; ++j) sacc[i][j] = f32x4{0.f, 0.f, 0.f, 0.f};
#pragma unroll
      for (int j = 0; j < 8; ++j) {
#pragma unroll
        for (int dc = 0; dc < 2; ++dc) {
          bf16x8 kf = *(const bf16x8*)(K + (j * 2 + dc) * 512 + lane * 8);
          sacc[0][j] = MFMA16(kf, aq[gq][0][dc], sacc[0][j]);
          sacc[1][j] = MFMA16(kf, aq[gq][1][dc], sacc[1][j]);
        }
      }
      // softmax (no max subtraction; logits bounded)
#pragma unroll
      for (int j = 0; j < 8; ++j) {
        f32x4 md = *(const f32x4*)&mrow[j * 16 + quad * 4];
#pragma unroll
        for (int i = 0; i < 2; ++i)
#pragma unroll
          for (int r = 0; r < 4; ++r)
            sacc[i][j][r] = __builtin_amdgcn_exp2f(fmaf(sacc[i][j][r], SC, md[r]));
      }
      // O += P V, l += P·1 (P frags in-register; slot order matches vt16)
#pragma unroll
      for (int c = 0; c < 4; ++c) {
        bf16x8 pf[2];
#pragma unroll
        for (int i = 0; i < 2; ++i) {
          bf16x2* p2 = (bf16x2*)&pf[i];
          p2[0] = cvt_pk_bf16(sacc[i][2 * c][0], sacc[i][2 * c][1]);
          p2[1] = cvt_pk_bf16(sacc[i][2 * c][2], sacc[i][2 * c][3]);
          p2[2] = cvt_pk_bf16(sacc[i][2 * c + 1][0], sacc[i][2 * c + 1][1]);
          p2[3] = cvt_pk_bf16(sacc[i][2 * c + 1][2], sacc[i][2 * c + 1][3]);
        }
#pragma unroll
        for (int n = 0; n < 4; ++n) {
          bf16x8 vv = *(const bf16x8*)(V + (n * 4 + c) * 512 + lane * 8);
          oacc[gq][0][n] = MFMA16(pf[0], vv, oacc[gq][0][n]);
          oacc[gq][1][n] = MFMA16(pf[1], vv, oacc[gq][1][n]);
        }
        lacc[gq][0] = MFMA16(pf[0], ones, lacc[gq][0]);
        lacc[gq][1] = MFMA16(pf[1], ones, lacc[gq][1]);
      }
    }
  }

  // epilogue: l already in C-layout rows — normalize & store
#pragma unroll
  for (int gq = 0; gq < 2; ++gq)
#pragma unroll
    for (int i = 0; i < 2; ++i)
#pragma unroll
      for (int r = 0; r < 4; ++r) {
        const float inv = 1.0f / lacc[gq][i][r];
        const int row = qt * 256 + gq * 128 + wave * 32 + i * 16 + quad * 4 + r;
#pragma unroll
        for (int n = 0; n < 4; ++n) {
          o16[((size_t)(b * 2048 + row)) * 1024 + h * 64 + n * 16 + fm] =
              (bf16_t)(oacc[gq][i][n][r] * inv);
        }
      }
}

// ---------------- launch ----------------
extern "C" void kernel_launch(void* const* d_in, const int* in_sizes, int n_in,
                              void* d_out, int out_size, void* d_ws, size_t ws_size,
                              hipStream_t stream) {
  const float* query = (const float*)d_in[0];
  const float* key   = (const float*)d_in[1];
  const float* value = (const float*)d_in[2];
  const int* mask    = (const int*)d_in[3];
  const float* Wq = (const float*)d_in[4];
  const float* bq = (const float*)d_in[5];
  const float* Wk = (const float*)d_in[6];
  const float* bk = (const float*)d_in[7];
  const float* Wv = (const float*)d_in[8];
  const float* bv = (const float*)d_in[9];
  const float* Wo = (const float*)d_in[10];
  const float* bo = (const float*)d_in[11];

  const size_t MB = 1024 * 1024;
  char* ws = (char*)d_ws;
  bf16_t* W16  = (bf16_t*)ws;                 // 8 MB
  bf16_t* q16  = (bf16_t*)(ws + 8 * MB);      // 16 MB
  bf16_t* k16  = (bf16_t*)(ws + 24 * MB);     // 16 MB
  bf16_t* vt16 = (bf16_t*)(ws + 40 * MB);     // 16 MB
  const bool big = ws_size >= 104 * MB;
  bf16_t* qf = (bf16_t*)(ws + 56 * MB);       // big: bf16 activations
  bf16_t* kf = (bf16_t*)(ws + 72 * MB);
  bf16_t* vf = (bf16_t*)(ws + 88 * MB);
  bf16_t* o16 = big ? qf : (bf16_t*)(ws + 56 * MB);  // o16 aliases qf (qf dead by attn)

  conv_kernel<<<big ? 28672 : 4096, 256, 0, stream>>>(query, key, value, Wq, Wk, Wv, Wo,
                                                      qf, kf, vf, W16);

  GArgs pa;
  pa.Wz[0] = W16; pa.Wz[1] = W16 + 1048576; pa.Wz[2] = W16 + 2097152;
  pa.bias[0] = bq; pa.bias[1] = bk; pa.bias[2] = bv;
  pa.out[0] = q16; pa.out[1] = k16; pa.out[2] = vt16;
  pa.mode[0] = 0; pa.mode[1] = 0; pa.mode[2] = 1;
  if (big) {
    pa.A[0] = qf; pa.A[1] = kf; pa.A[2] = vf;
    gemm256<false><<<dim3(32, 8, 3), 512, 0, stream>>>(pa);
  } else {
    pa.A[0] = query; pa.A[1] = key; pa.A[2] = value;
    gemm256<true><<<dim3(32, 8, 3), 512, 0, stream>>>(pa);
  }

  attn_kernel<<<512, 256, 0, stream>>>(q16, k16, vt16, mask, o16);

  GArgs oa;
  oa.A[0] = o16; oa.Wz[0] = W16 + 3145728; oa.bias[0] = bo;
  oa.out[0] = d_out; oa.mode[0] = 2;
  oa.A[1] = oa.A[2] = nullptr; oa.Wz[1] = oa.Wz[2] = nullptr;
  oa.bias[1] = oa.bias[2] = nullptr; oa.out[1] = oa.out[2] = nullptr;
  oa.mode[1] = oa.mode[2] = 2;
  gemm256<false><<<dim3(32, 8, 1), 512, 0, stream>>>(oa);
}